// Round 1
// 202.065 us; speedup vs baseline: 1.9239x; 1.9239x over previous
//
#include <hip/hip_runtime.h>
#include <hip/hip_bf16.h>
#include <stdint.h>

// Problem constants
#define NB   8
#define KL   512
#define QD   16
#define SD   128
#define ED   256
#define RPN  (QD*SD)   // 2048 rows (q,s) per n
#define BMR  32        // query rows per fused-attention block

typedef __hip_bfloat16 bf16;
using s16x8 = __attribute__((ext_vector_type(8))) short;  // 8 bf16 = 4 VGPRs
using f32x4 = __attribute__((ext_vector_type(4))) float;  // MFMA accumulator

__device__ __forceinline__ float b2f(unsigned short u){
    union { uint32_t i; float f; } v; v.i = ((uint32_t)u) << 16; return v.f;
}
__device__ __forceinline__ unsigned short f2b(float f){
    union { float ff; uint32_t i; } v; v.ff = f;
    uint32_t lsb = (v.i >> 16) & 1;
    v.i += 0x7FFFu + lsb;               // RNE
    return (unsigned short)(v.i >> 16);
}
__device__ __forceinline__ uint32_t cvtpk(float lo, float hi){
    uint32_t r;
    asm("v_cvt_pk_bf16_f32 %0, %1, %2" : "=v"(r) : "v"(lo), "v"(hi));
    return r;
}
__device__ __forceinline__ f32x4 mfma16(s16x8 a, s16x8 b, f32x4 c){
    return __builtin_amdgcn_mfma_f32_16x16x32_bf16(a, b, c, 0, 0, 0);
}

template<bool B>
__device__ __forceinline__ float ldin(const void* p, size_t i){
    if (B) return b2f(((const unsigned short*)p)[i]);
    else   return ((const float*)p)[i];
}

// ---------------- dtype probe ----------------
__global__ void k_probe(const uint32_t* __restrict__ w, int* __restrict__ flag){
    __shared__ int cnt;
    if (threadIdx.x == 0) cnt = 0;
    __syncthreads();
    int local = 0;
    #pragma unroll
    for (int i = 0; i < 4; ++i){
        uint32_t x = w[threadIdx.x*4 + i];
        uint32_t e = (x >> 7) & 0xFFu;
        local += (e >= 120u && e <= 132u) ? 1 : 0;
    }
    atomicAdd(&cnt, local);
    __syncthreads();
    if (threadIdx.x == 0) *flag = (cnt > 512) ? 1 : 0;
}

// ---------------- weight prep ----------------
template<bool B>
__global__ void k_wosum(const void* __restrict__ Wo, const int* __restrict__ flag,
                        float* __restrict__ wos){
    if (*flag != (B ? 1 : 0)) return;
    int idx = blockIdx.x*256 + threadIdx.x;   // e*256+d
    int e = idx >> 8, d = idx & 255;
    float s = 0.f;
    #pragma unroll
    for (int h = 0; h < 8; ++h) s += ldin<B>(Wo, (size_t)e*2048 + h*256 + d);
    wos[idx] = s;
}

template<bool B>
__global__ void k_gt(const void* __restrict__ Wq, const void* __restrict__ Wk,
                     const int* __restrict__ flag, float* __restrict__ Gt){
    if (*flag != (B ? 1 : 0)) return;
    int b = blockIdx.x, a = threadIdx.x;
    float s = 0.f;
    for (int d = 0; d < 256; ++d)
        s += ldin<B>(Wq, (size_t)d*256 + a) * ldin<B>(Wk, (size_t)d*256 + b);
    Gt[b*256 + a] = s;
}

template<bool B>
__global__ void k_mt(const float* __restrict__ wos, const void* __restrict__ Wv,
                     const int* __restrict__ flag, float* __restrict__ Mt){
    if (*flag != (B ? 1 : 0)) return;
    int d = blockIdx.x, e = threadIdx.x;
    float s = 0.f;
    for (int dp = 0; dp < 256; ++dp)
        s += wos[e*256 + dp] * ldin<B>(Wv, (size_t)dp*256 + d);
    Mt[d*256 + e] = s;
}

// ---------------- projections ----------------
// C[r,o] = sum_i A[r,i] * Wt[i*256+o]; natural [row][o] bf16 output (for kk).
template<bool B>
__global__ __launch_bounds__(256)
void k_proj(const void* __restrict__ A, const float* __restrict__ Wt,
            const int* __restrict__ flag, unsigned short* __restrict__ C){
    if (*flag != (B ? 1 : 0)) return;
    __shared__ float As[8][256];
    int r0 = blockIdx.x * 8;
    int t  = threadIdx.x;
    #pragma unroll
    for (int j = 0; j < 8; ++j)
        As[j][t] = ldin<B>(A, (size_t)(r0 + j)*256 + t);
    __syncthreads();
    float acc[8] = {0,0,0,0,0,0,0,0};
    for (int i = 0; i < 256; ++i){
        float w = Wt[i*256 + t];
        #pragma unroll
        for (int j = 0; j < 8; ++j) acc[j] += As[j][i] * w;
    }
    #pragma unroll
    for (int j = 0; j < 8; ++j)
        C[(size_t)(r0 + j)*256 + t] = f2b(acc[j]);
}

// Transposed variant (for u): stores C_t[n][e][k], k contiguous, so the fused
// kernel's GEMM2 B-fragments (8 consecutive k per lane) are 16B vector loads.
// Thread t holds column e=t for the block's 8 consecutive k rows -> one 16B store.
template<bool B>
__global__ __launch_bounds__(256)
void k_projT(const void* __restrict__ A, const float* __restrict__ Wt,
             const int* __restrict__ flag, unsigned short* __restrict__ C){
    if (*flag != (B ? 1 : 0)) return;
    __shared__ float As[8][256];
    int r0 = blockIdx.x * 8;           // rows are (n,k) flattened, 512 per n
    int t  = threadIdx.x;
    #pragma unroll
    for (int j = 0; j < 8; ++j)
        As[j][t] = ldin<B>(A, (size_t)(r0 + j)*256 + t);
    __syncthreads();
    float acc[8] = {0,0,0,0,0,0,0,0};
    for (int i = 0; i < 256; ++i){
        float w = Wt[i*256 + t];
        #pragma unroll
        for (int j = 0; j < 8; ++j) acc[j] += As[j][i] * w;
    }
    int nn = r0 >> 9, k0 = r0 & 511;
    union { s16x8 v; unsigned short h[8]; } pk;
    #pragma unroll
    for (int j = 0; j < 8; ++j) pk.h[j] = f2b(acc[j]);
    *(s16x8*)(&C[(size_t)nn*ED*KL + (size_t)t*KL + k0]) = pk.v;
}

// ---------------- fused: MFMA QK^T -> masked softmax -> MFMA PV -> +bo -------
// Block: 32 query rows x full 512 keys, 4 waves.
// GEMM1: wave w owns all 32 rows x keys [w*128, w*128+128).
// GEMM2: wave w owns all 32 rows x e    [w*64,  w*64+64).
// Scores live in a 64KB LDS buffer, element-XOR-swizzled (idx ^ ((row&7)<<2))
// so the stride-2KB A-fragment ds_read_b128s are bank-conflict-free (T2).
// Softmax writes NORMALIZED P in place -> no invs buffer, LDS stays at 64KB
// -> 2 blocks/CU.
template<bool B>
__global__ __launch_bounds__(256, 2)
void k_fused(const void* __restrict__ query, const unsigned short* __restrict__ kk,
             const unsigned short* __restrict__ ut, const int* __restrict__ mask,
             const void* __restrict__ bo, const int* __restrict__ flag,
             void* __restrict__ out){
    if (*flag != (B ? 1 : 0)) return;
    __shared__ float Sc[BMR * KL];     // 65536 B exactly

    int n  = blockIdx.y;
    int r0 = blockIdx.x * BMR;
    int t  = threadIdx.x;
    int l15 = t & 15;
    int g   = (t >> 4) & 3;            // 16-lane group within wave
    int w   = t >> 6;                  // wave 0..3

    const unsigned short* Kn = kk + (size_t)n*KL*ED;   // [key][e] bf16
    const unsigned short* Un = ut + (size_t)n*ED*KL;   // [e][k]   bf16
    const int* mn = mask + n*KL;

    // ---- A-fragments: Q rows r0..r0+31 (2 row-tiles), cast to bf16 ----
    // MFMA A layout: lane holds row = l&15, k = 8*(l>>4 & 3) + 0..7 (contig 16B).
    s16x8 aq[2][8];
    #pragma unroll
    for (int rt = 0; rt < 2; ++rt){
        size_t qoff = (size_t)n*RPN*ED + (size_t)(r0 + rt*16 + l15)*ED + g*8;
        if (B){
            const unsigned short* qp = (const unsigned short*)query + qoff;
            #pragma unroll
            for (int kt = 0; kt < 8; ++kt)
                aq[rt][kt] = *(const s16x8*)(qp + kt*32);
        } else {
            const float* qp = (const float*)query + qoff;
            #pragma unroll
            for (int kt = 0; kt < 8; ++kt){
                float4 x0 = *(const float4*)(qp + kt*32);
                float4 x1 = *(const float4*)(qp + kt*32 + 4);
                union { s16x8 v; uint32_t u[4]; } pk;
                pk.u[0] = cvtpk(x0.x, x0.y);
                pk.u[1] = cvtpk(x0.z, x0.w);
                pk.u[2] = cvtpk(x1.x, x1.y);
                pk.u[3] = cvtpk(x1.z, x1.w);
                aq[rt][kt] = pk.v;
            }
        }
    }

    // ---- GEMM1: S[32 x 128-key strip] = Q . kk^T ----
    {
        f32x4 acc[2][8];
        #pragma unroll
        for (int rt = 0; rt < 2; ++rt)
            #pragma unroll
            for (int ct = 0; ct < 8; ++ct) acc[rt][ct] = (f32x4){0.f,0.f,0.f,0.f};

        // B fragment: lane needs kk[(key0 + l&15)][kt*32 + 8*g + 0..7] -> 16B.
        const unsigned short* kp0 = Kn + (size_t)(w*128 + l15)*ED + g*8;
        #pragma unroll
        for (int ct = 0; ct < 8; ++ct){
            #pragma unroll
            for (int kt = 0; kt < 8; ++kt){
                s16x8 b = *(const s16x8*)(kp0 + (size_t)ct*16*ED + kt*32);
                acc[0][ct] = mfma16(aq[0][kt], b, acc[0][ct]);
                acc[1][ct] = mfma16(aq[1][kt], b, acc[1][ct]);
            }
        }
        // epilogue: mask + scale -> swizzled LDS.
        // C layout: row = 4*g + reg, col(key) = l&15.
        #pragma unroll
        for (int ct = 0; ct < 8; ++ct){
            int key = w*128 + ct*16 + l15;
            bool zz = (mn[key] == 0);
            #pragma unroll
            for (int rt = 0; rt < 2; ++rt){
                #pragma unroll
                for (int j = 0; j < 4; ++j){
                    int row = rt*16 + g*4 + j;
                    float v = zz ? -1e20f : acc[rt][ct][j] * 0.0625f;
                    Sc[(row*KL + key) ^ ((row & 7) << 2)] = v;
                }
            }
        }
    }
    __syncthreads();

    // ---- masked softmax, normalized in place (16 threads/row, 2 passes) ----
    {
        int l16 = t & 15;
        #pragma unroll
        for (int half = 0; half < 2; ++half){
            int row  = half*16 + (t >> 4);
            int sw   = (row & 7) << 2;
            int base = row*KL + l16;
            float xs[32];
            float m = -3.0e38f;
            #pragma unroll
            for (int i = 0; i < 32; ++i){
                xs[i] = Sc[(base + 16*i) ^ sw];
                m = fmaxf(m, xs[i]);
            }
            #pragma unroll
            for (int off = 1; off < 16; off <<= 1)
                m = fmaxf(m, __shfl_xor(m, off, 16));
            float s = 0.f;
            #pragma unroll
            for (int i = 0; i < 32; ++i){
                xs[i] = __expf(xs[i] - m);
                s += xs[i];
            }
            #pragma unroll
            for (int off = 1; off < 16; off <<= 1)
                s += __shfl_xor(s, off, 16);
            float inv = 1.0f / s;
            #pragma unroll
            for (int i = 0; i < 32; ++i)
                Sc[(base + 16*i) ^ sw] = xs[i] * inv;
        }
    }
    __syncthreads();

    // ---- GEMM2: Out[32 x 64-e strip] = P . u  (u consumed via ut[e][k]) ----
    {
        f32x4 acc[2][4];
        #pragma unroll
        for (int rt = 0; rt < 2; ++rt)
            #pragma unroll
            for (int ct = 0; ct < 4; ++ct) acc[rt][ct] = (f32x4){0.f,0.f,0.f,0.f};

        const unsigned short* up0 = Un + (size_t)(w*64 + l15)*KL + g*8;
        #pragma unroll
        for (int kt = 0; kt < 16; ++kt){
            // A fragments (P) from swizzled LDS, fp32 -> bf16 via v_cvt_pk.
            s16x8 ap[2];
            #pragma unroll
            for (int rt = 0; rt < 2; ++rt){
                int row  = rt*16 + l15;
                int sw   = (row & 7) << 2;
                int base = row*KL + kt*32 + g*8;
                float4 a0 = *(const float4*)&Sc[(base    ) ^ sw];
                float4 a1 = *(const float4*)&Sc[(base + 4) ^ sw];
                union { s16x8 v; uint32_t u[4]; } pk;
                pk.u[0] = cvtpk(a0.x, a0.y);
                pk.u[1] = cvtpk(a0.z, a0.w);
                pk.u[2] = cvtpk(a1.x, a1.y);
                pk.u[3] = cvtpk(a1.z, a1.w);
                ap[rt] = pk.v;
            }
            #pragma unroll
            for (int ct = 0; ct < 4; ++ct){
                s16x8 b = *(const s16x8*)(up0 + (size_t)ct*16*KL + kt*32);
                acc[0][ct] = mfma16(ap[0], b, acc[0][ct]);
                acc[1][ct] = mfma16(ap[1], b, acc[1][ct]);
            }
        }
        // epilogue: + bo, store (P already normalized)
        #pragma unroll
        for (int rt = 0; rt < 2; ++rt){
            #pragma unroll
            for (int j = 0; j < 4; ++j){
                int row = rt*16 + g*4 + j;
                #pragma unroll
                for (int ct = 0; ct < 4; ++ct){
                    int e = w*64 + ct*16 + l15;
                    float val = acc[rt][ct][j] + ldin<B>(bo, e);
                    size_t oidx = (size_t)n*RPN*ED + (size_t)(r0 + row)*ED + e;
                    if (B) ((unsigned short*)out)[oidx] = f2b(val);
                    else   ((float*)out)[oidx] = val;
                }
            }
        }
    }
}

// ---------------- launch ----------------
extern "C" void kernel_launch(void* const* d_in, const int* in_sizes, int n_in,
                              void* d_out, int out_size, void* d_ws, size_t ws_size,
                              hipStream_t stream){
    const void* values = d_in[0];
    const void* keys   = d_in[1];
    const void* query  = d_in[2];
    const int*  mask   = (const int*)d_in[3];
    const void* Wv     = d_in[4];
    const void* Wk     = d_in[5];
    const void* Wq     = d_in[6];
    const void* Wo     = d_in[7];
    const void* bo     = d_in[8];

    // ws layout (floats): [flag pad 64][wos 65536][gt 65536][mt 65536]
    //                     [kk bf16 1Mi elem][ut bf16 1Mi elem (transposed)]
    float* ws = (float*)d_ws;
    int*   ws_flag = (int*)ws;
    float* ws_wos  = ws + 64;
    float* ws_gt   = ws + 64 + 65536;
    float* ws_mt   = ws + 64 + 131072;
    unsigned short* ws_kk = (unsigned short*)(ws + 64 + 196608);
    unsigned short* ws_u  = ws_kk + (size_t)NB*KL*ED;

    k_probe<<<1, 256, 0, stream>>>((const uint32_t*)values, ws_flag);

    k_wosum<true ><<<256, 256, 0, stream>>>(Wo, ws_flag, ws_wos);
    k_wosum<false><<<256, 256, 0, stream>>>(Wo, ws_flag, ws_wos);
    k_gt   <true ><<<256, 256, 0, stream>>>(Wq, Wk, ws_flag, ws_gt);
    k_gt   <false><<<256, 256, 0, stream>>>(Wq, Wk, ws_flag, ws_gt);
    k_mt   <true ><<<256, 256, 0, stream>>>(ws_wos, Wv, ws_flag, ws_mt);
    k_mt   <false><<<256, 256, 0, stream>>>(ws_wos, Wv, ws_flag, ws_mt);

    k_proj <true ><<<512, 256, 0, stream>>>(keys,   ws_gt, ws_flag, ws_kk);
    k_proj <false><<<512, 256, 0, stream>>>(keys,   ws_gt, ws_flag, ws_kk);
    k_projT<true ><<<512, 256, 0, stream>>>(values, ws_mt, ws_flag, ws_u);
    k_projT<false><<<512, 256, 0, stream>>>(values, ws_mt, ws_flag, ws_u);

    k_fused<true ><<<dim3(RPN/BMR, NB), 256, 0, stream>>>(query, ws_kk, ws_u, mask, bo, ws_flag, d_out);
    k_fused<false><<<dim3(RPN/BMR, NB), 256, 0, stream>>>(query, ws_kk, ws_u, mask, bo, ws_flag, d_out);
}

// Round 2
// 174.051 us; speedup vs baseline: 2.2335x; 1.1610x over previous
//
#include <hip/hip_runtime.h>
#include <hip/hip_bf16.h>
#include <stdint.h>

// Problem constants
#define NB   8
#define KL   512
#define QD   16
#define SD   128
#define ED   256
#define RPN  (QD*SD)   // 2048 rows (q,s) per n
#define BMR  32        // query rows per fused-attention block

typedef __hip_bfloat16 bf16;
using s16x8 = __attribute__((ext_vector_type(8))) short;  // 8 bf16 = 4 VGPRs
using f32x4 = __attribute__((ext_vector_type(4))) float;  // MFMA accumulator

__device__ __forceinline__ float b2f(unsigned short u){
    union { uint32_t i; float f; } v; v.i = ((uint32_t)u) << 16; return v.f;
}
__device__ __forceinline__ unsigned short f2b(float f){
    union { float ff; uint32_t i; } v; v.ff = f;
    uint32_t lsb = (v.i >> 16) & 1;
    v.i += 0x7FFFu + lsb;               // RNE
    return (unsigned short)(v.i >> 16);
}
__device__ __forceinline__ uint32_t cvtpk(float lo, float hi){
    uint32_t r;
    asm("v_cvt_pk_bf16_f32 %0, %1, %2" : "=v"(r) : "v"(lo), "v"(hi));
    return r;
}
__device__ __forceinline__ f32x4 mfma16(s16x8 a, s16x8 b, f32x4 c){
    return __builtin_amdgcn_mfma_f32_16x16x32_bf16(a, b, c, 0, 0, 0);
}

template<bool B>
__device__ __forceinline__ float ldin(const void* p, size_t i){
    if (B) return b2f(((const unsigned short*)p)[i]);
    else   return ((const float*)p)[i];
}

// ---------------- dtype probe ----------------
__global__ void k_probe(const uint32_t* __restrict__ w, int* __restrict__ flag){
    __shared__ int cnt;
    if (threadIdx.x == 0) cnt = 0;
    __syncthreads();
    int local = 0;
    #pragma unroll
    for (int i = 0; i < 4; ++i){
        uint32_t x = w[threadIdx.x*4 + i];
        uint32_t e = (x >> 7) & 0xFFu;
        local += (e >= 120u && e <= 132u) ? 1 : 0;
    }
    atomicAdd(&cnt, local);
    __syncthreads();
    if (threadIdx.x == 0) *flag = (cnt > 512) ? 1 : 0;
}

// ---------------- merged weight prep: gt (blocks 0-255) + wosum (256-511) ---
template<bool B>
__device__ void gt_body(const void* __restrict__ Wq, const void* __restrict__ Wk,
                        float* __restrict__ Gt, int bx){
    int b = bx, a = threadIdx.x;
    float s = 0.f;
    #pragma unroll 8
    for (int d = 0; d < 256; ++d)
        s += ldin<B>(Wq, (size_t)d*256 + a) * ldin<B>(Wk, (size_t)d*256 + b);
    Gt[b*256 + a] = s;
}
template<bool B>
__device__ void wosum_body(const void* __restrict__ Wo, float* __restrict__ wos, int bx){
    int idx = bx*256 + threadIdx.x;   // e*256+d
    int e = idx >> 8, d = idx & 255;
    float s = 0.f;
    #pragma unroll
    for (int h = 0; h < 8; ++h) s += ldin<B>(Wo, (size_t)e*2048 + h*256 + d);
    wos[idx] = s;
}
__global__ void k_prep1(const void* __restrict__ Wq, const void* __restrict__ Wk,
                        const void* __restrict__ Wo, const int* __restrict__ flag,
                        float* __restrict__ Gt, float* __restrict__ wos){
    bool bf = (*flag != 0);
    if (blockIdx.x < 256){
        if (bf) gt_body<true >(Wq, Wk, Gt, blockIdx.x);
        else    gt_body<false>(Wq, Wk, Gt, blockIdx.x);
    } else {
        int bx = blockIdx.x - 256;
        if (bf) wosum_body<true >(Wo, wos, bx);
        else    wosum_body<false>(Wo, wos, bx);
    }
}

// Mt[d*256+e] = sum_dp wos[e*256+dp]*Wv[dp*256+d]
template<bool B>
__device__ void mt_body(const float* __restrict__ wos, const void* __restrict__ Wv,
                        float* __restrict__ Mt){
    int d = blockIdx.x, e = threadIdx.x;
    float s = 0.f;
    #pragma unroll 8
    for (int dp = 0; dp < 256; ++dp)
        s += wos[e*256 + dp] * ldin<B>(Wv, (size_t)dp*256 + d);
    Mt[d*256 + e] = s;
}
__global__ void k_mt2(const float* __restrict__ wos, const void* __restrict__ Wv,
                      const int* __restrict__ flag, float* __restrict__ Mt){
    if (*flag) mt_body<true >(wos, Wv, Mt);
    else       mt_body<false>(wos, Wv, Mt);
}

// ---------------- merged projections ----------------
// blocks 0-511:   kk[n][key][e] = keys @ Gt          (natural layout, bf16)
// blocks 512-1023: ut[n][e][k]  = (values @ Mt)^T    (k contiguous, bf16)
template<bool B>
__device__ void proj_body(const void* __restrict__ A, const float* __restrict__ Wt,
                          unsigned short* __restrict__ C, int bx, bool transT,
                          float (*As)[256]){
    int r0 = bx * 8;
    int t  = threadIdx.x;
    #pragma unroll
    for (int j = 0; j < 8; ++j)
        As[j][t] = ldin<B>(A, (size_t)(r0 + j)*256 + t);
    __syncthreads();
    float acc[8] = {0,0,0,0,0,0,0,0};
    #pragma unroll 4
    for (int i = 0; i < 256; ++i){
        float w = Wt[i*256 + t];
        #pragma unroll
        for (int j = 0; j < 8; ++j) acc[j] += As[j][i] * w;
    }
    if (!transT){
        #pragma unroll
        for (int j = 0; j < 8; ++j)
            C[(size_t)(r0 + j)*256 + t] = f2b(acc[j]);
    } else {
        int nn = r0 >> 9, k0 = r0 & 511;
        union { s16x8 v; unsigned short h[8]; } pk;
        #pragma unroll
        for (int j = 0; j < 8; ++j) pk.h[j] = f2b(acc[j]);
        *(s16x8*)(&C[(size_t)nn*ED*KL + (size_t)t*KL + k0]) = pk.v;
    }
}
__global__ __launch_bounds__(256)
void k_proj2(const void* __restrict__ keys, const void* __restrict__ values,
             const float* __restrict__ Gt, const float* __restrict__ Mt,
             const int* __restrict__ flag,
             unsigned short* __restrict__ kkv, unsigned short* __restrict__ utv){
    __shared__ float As[8][256];
    bool bf = (*flag != 0);
    if (blockIdx.x < 512){
        if (bf) proj_body<true >(keys, Gt, kkv, blockIdx.x, false, As);
        else    proj_body<false>(keys, Gt, kkv, blockIdx.x, false, As);
    } else {
        int bx = blockIdx.x - 512;
        if (bf) proj_body<true >(values, Mt, utv, bx, true, As);
        else    proj_body<false>(values, Mt, utv, bx, true, As);
    }
}

// ---------------- fused: MFMA QK^T -> masked softmax -> MFMA PV -> +bo -------
// 512 threads = 8 waves; 32 q-rows x 512 keys per block.
// LDS: Sc fp32 64KB (scores; first 32KB reused as bf16 P) + Qs bf16 16KB = 80KB
//   -> 2 blocks/CU = 16 waves/CU (needs VGPR<=128 via __launch_bounds__(512,4)).
// GEMM1: wave w owns keys [w*64, w*64+64): 4 ct x 8 kt x 2 rt = 64 MFMA.
//        B fragments pipelined 2 k-steps deep in rotating regs (8 loads in flight).
// GEMM2: wave w owns e [w*32, w*32+32): 2 ct x 16 kt x 2 rt = 64 MFMA.
//        P read as bf16 directly (softmax wrote bf16 back), B pipelined 3 deep.
// XCD swizzle: n = bid&7 pins each batch's kk/ut panels (512KB) to one XCD L2.
template<bool B>
__device__ void fused_body(const void* __restrict__ query,
                           const unsigned short* __restrict__ kk,
                           const unsigned short* __restrict__ ut,
                           const int* __restrict__ mask,
                           const void* __restrict__ bo,
                           void* __restrict__ out,
                           float* Sc, unsigned short* Qs){
    int bid = blockIdx.x;
    int n   = bid & 7;                 // all 64 blocks of a batch on one XCD
    int r0  = (bid >> 3) * BMR;
    int t   = threadIdx.x;
    int l15 = t & 15;
    int g   = (t >> 4) & 3;            // 16-lane group within wave
    int w   = t >> 6;                  // wave 0..7

    const unsigned short* Kn = kk + (size_t)n*KL*ED;   // [key][e]
    const unsigned short* Un = ut + (size_t)n*ED*KL;   // [e][k]
    const int* mn = mask + n*KL;
    unsigned short* P = (unsigned short*)Sc;           // bf16 P aliases Sc[0:32KB)

    // ---- phase 0: stage Q tile to LDS as bf16, XOR-swizzled ----
    {
        int row = t >> 4;              // 0..31
        int c0  = (t & 15) * 16;
        int sw  = (row & 7) << 3;      // 8-elem (16B) granularity
        size_t qoff = (size_t)n*RPN*ED + (size_t)(r0 + row)*ED + c0;
        if (B){
            const unsigned short* qp = (const unsigned short*)query + qoff;
            s16x8 v0 = *(const s16x8*)(qp);
            s16x8 v1 = *(const s16x8*)(qp + 8);
            *(s16x8*)&Qs[(row*ED + c0    ) ^ sw] = v0;
            *(s16x8*)&Qs[(row*ED + c0 + 8) ^ sw] = v1;
        } else {
            const float* qp = (const float*)query + qoff;
            float4 x0 = *(const float4*)(qp);
            float4 x1 = *(const float4*)(qp + 4);
            float4 x2 = *(const float4*)(qp + 8);
            float4 x3 = *(const float4*)(qp + 12);
            union { s16x8 v; uint32_t u[4]; } pk;
            pk.u[0] = cvtpk(x0.x,x0.y); pk.u[1] = cvtpk(x0.z,x0.w);
            pk.u[2] = cvtpk(x1.x,x1.y); pk.u[3] = cvtpk(x1.z,x1.w);
            *(s16x8*)&Qs[(row*ED + c0    ) ^ sw] = pk.v;
            pk.u[0] = cvtpk(x2.x,x2.y); pk.u[1] = cvtpk(x2.z,x2.w);
            pk.u[2] = cvtpk(x3.x,x3.y); pk.u[3] = cvtpk(x3.z,x3.w);
            *(s16x8*)&Qs[(row*ED + c0 + 8) ^ sw] = pk.v;
        }
    }
    __syncthreads();

    // ---- phase 1: GEMM1, S[32 x 64-key strip] = Q . kk^T ----
    {
        f32x4 acc1[2][4];
        #pragma unroll
        for (int rt = 0; rt < 2; ++rt)
            #pragma unroll
            for (int c = 0; c < 4; ++c) acc1[rt][c] = (f32x4){0.f,0.f,0.f,0.f};

        const unsigned short* kp0 = Kn + (size_t)(w*64 + l15)*ED + g*8;
        s16x8 bb[3][4];                // rotating buffer, 2 k-steps ahead
        auto LDK = [&](int KT, int SL){
            #pragma unroll
            for (int c = 0; c < 4; ++c)
                bb[SL][c] = *(const s16x8*)(kp0 + (size_t)(c*16*ED + KT*32));
        };
        LDK(0,0); LDK(1,1);
        int asw = (l15 & 7) << 3;      // same for row l15 and 16+l15
        #pragma unroll
        for (int kt = 0; kt < 8; ++kt){
            if (kt + 2 < 8) LDK(kt + 2, (kt + 2) % 3);
            int col = kt*32 + g*8;
            s16x8 a0 = *(const s16x8*)&Qs[(( 0 + l15)*ED + col) ^ asw];
            s16x8 a1 = *(const s16x8*)&Qs[((16 + l15)*ED + col) ^ asw];
            #pragma unroll
            for (int c = 0; c < 4; ++c){
                acc1[0][c] = mfma16(a0, bb[kt % 3][c], acc1[0][c]);
                acc1[1][c] = mfma16(a1, bb[kt % 3][c], acc1[1][c]);
            }
        }
        // epilogue: mask + scale -> swizzled LDS (f32)
        #pragma unroll
        for (int c = 0; c < 4; ++c){
            int key = w*64 + c*16 + l15;
            bool zz = (mn[key] == 0);
            #pragma unroll
            for (int rt = 0; rt < 2; ++rt){
                #pragma unroll
                for (int j = 0; j < 4; ++j){
                    int row = rt*16 + g*4 + j;
                    float v = zz ? -1e20f : acc1[rt][c][j] * 0.0625f;
                    Sc[(row*KL + key) ^ ((row & 7) << 2)] = v;
                }
            }
        }
    }
    __syncthreads();

    // ---- phase 2: masked softmax, 16 threads/row, write P back as bf16 ----
    {
        int row = t >> 4, l16 = t & 15;
        int sw2 = (row & 7) << 2, sw3 = (row & 7) << 3;
        float xs[32];
        float m = -3.0e38f;
        #pragma unroll
        for (int i = 0; i < 32; ++i){
            xs[i] = Sc[(row*KL + l16 + 16*i) ^ sw2];
            m = fmaxf(m, xs[i]);
        }
        #pragma unroll
        for (int off = 1; off < 16; off <<= 1)
            m = fmaxf(m, __shfl_xor(m, off, 16));
        float s = 0.f;
        #pragma unroll
        for (int i = 0; i < 32; ++i){
            xs[i] = __expf(xs[i] - m);
            s += xs[i];
        }
        #pragma unroll
        for (int off = 1; off < 16; off <<= 1)
            s += __shfl_xor(s, off, 16);
        float inv = 1.0f / s;
        __syncthreads();               // all f32 score reads done before aliasing
        #pragma unroll
        for (int i = 0; i < 32; ++i)
            P[(row*KL + l16 + 16*i) ^ sw3] = f2b(xs[i] * inv);
    }
    __syncthreads();

    // ---- phase 3: GEMM2, Out[32 x 32-e strip] = P . u (ut[e][k]) ----
    {
        f32x4 acc2[2][2];
        #pragma unroll
        for (int rt = 0; rt < 2; ++rt)
            #pragma unroll
            for (int c = 0; c < 2; ++c) acc2[rt][c] = (f32x4){0.f,0.f,0.f,0.f};

        const unsigned short* up0 = Un + (size_t)(w*32 + l15)*KL + g*8;
        s16x8 bu[4][2];                // rotating buffer, 3 k-steps ahead
        auto LDU = [&](int KT, int SL){
            #pragma unroll
            for (int c = 0; c < 2; ++c)
                bu[SL][c] = *(const s16x8*)(up0 + (size_t)(c*16*KL + KT*32));
        };
        LDU(0,0); LDU(1,1); LDU(2,2);
        int asw = (l15 & 7) << 3;
        #pragma unroll
        for (int kt = 0; kt < 16; ++kt){
            if (kt + 3 < 16) LDU(kt + 3, (kt + 3) & 3);
            int col = kt*32 + g*8;
            s16x8 p0 = *(const s16x8*)&P[(( 0 + l15)*KL + col) ^ asw];
            s16x8 p1 = *(const s16x8*)&P[((16 + l15)*KL + col) ^ asw];
            #pragma unroll
            for (int c = 0; c < 2; ++c){
                acc2[0][c] = mfma16(p0, bu[kt & 3][c], acc2[0][c]);
                acc2[1][c] = mfma16(p1, bu[kt & 3][c], acc2[1][c]);
            }
        }
        // epilogue: + bo, store (P already normalized)
        float bov[2];
        #pragma unroll
        for (int c = 0; c < 2; ++c) bov[c] = ldin<B>(bo, w*32 + c*16 + l15);
        #pragma unroll
        for (int rt = 0; rt < 2; ++rt){
            #pragma unroll
            for (int j = 0; j < 4; ++j){
                int row = rt*16 + g*4 + j;
                #pragma unroll
                for (int c = 0; c < 2; ++c){
                    int e = w*32 + c*16 + l15;
                    float val = acc2[rt][c][j] + bov[c];
                    size_t oidx = (size_t)n*RPN*ED + (size_t)(r0 + row)*ED + e;
                    if (B) ((unsigned short*)out)[oidx] = f2b(val);
                    else   ((float*)out)[oidx] = val;
                }
            }
        }
    }
}

__global__ __launch_bounds__(512, 4)
void k_fused2(const void* __restrict__ query, const unsigned short* __restrict__ kk,
              const unsigned short* __restrict__ ut, const int* __restrict__ mask,
              const void* __restrict__ bo, const int* __restrict__ flag,
              void* __restrict__ out){
    __shared__ float Sc[BMR*KL];           // 64 KB
    __shared__ unsigned short Qs[BMR*ED];  // 16 KB  (total 80 KB -> 2 blocks/CU)
    if (*flag) fused_body<true >(query, kk, ut, mask, bo, out, Sc, Qs);
    else       fused_body<false>(query, kk, ut, mask, bo, out, Sc, Qs);
}

// ---------------- launch ----------------
extern "C" void kernel_launch(void* const* d_in, const int* in_sizes, int n_in,
                              void* d_out, int out_size, void* d_ws, size_t ws_size,
                              hipStream_t stream){
    const void* values = d_in[0];
    const void* keys   = d_in[1];
    const void* query  = d_in[2];
    const int*  mask   = (const int*)d_in[3];
    const void* Wv     = d_in[4];
    const void* Wk     = d_in[5];
    const void* Wq     = d_in[6];
    const void* Wo     = d_in[7];
    const void* bo     = d_in[8];

    // ws layout (floats): [flag pad 64][wos 65536][gt 65536][mt 65536]
    //                     [kk bf16 1Mi elem][ut bf16 1Mi elem (transposed)]
    float* ws = (float*)d_ws;
    int*   ws_flag = (int*)ws;
    float* ws_wos  = ws + 64;
    float* ws_gt   = ws + 64 + 65536;
    float* ws_mt   = ws + 64 + 131072;
    unsigned short* ws_kk = (unsigned short*)(ws + 64 + 196608);
    unsigned short* ws_u  = ws_kk + (size_t)NB*KL*ED;

    k_probe<<<1, 256, 0, stream>>>((const uint32_t*)values, ws_flag);
    k_prep1<<<512, 256, 0, stream>>>(Wq, Wk, Wo, ws_flag, ws_gt, ws_wos);
    k_mt2  <<<256, 256, 0, stream>>>(ws_wos, Wv, ws_flag, ws_mt);
    k_proj2<<<1024, 256, 0, stream>>>(keys, values, ws_gt, ws_mt, ws_flag, ws_kk, ws_u);
    k_fused2<<<512, 512, 0, stream>>>(query, ws_kk, ws_u, mask, bo, ws_flag, d_out);
}

// Round 3
// 150.471 us; speedup vs baseline: 2.5835x; 1.1567x over previous
//
#include <hip/hip_runtime.h>
#include <hip/hip_bf16.h>
#include <stdint.h>

// Problem constants
#define NB   8
#define KL   512
#define QD   16
#define SD   128
#define ED   256
#define RPN  (QD*SD)   // 2048 rows (q,s) per n
#define BMR  32        // query rows per fused-attention block
#define FRAG 512       // elements per B-fragment (64 lanes x 8 bf16)
#define PAN  131072    // elements per n-panel of a fragment buffer (256 frags)

typedef __hip_bfloat16 bf16;
using s16x8 = __attribute__((ext_vector_type(8))) short;  // 8 bf16 = 4 VGPRs
using f32x4 = __attribute__((ext_vector_type(4))) float;  // MFMA accumulator

__device__ __forceinline__ float b2f(unsigned short u){
    union { uint32_t i; float f; } v; v.i = ((uint32_t)u) << 16; return v.f;
}
__device__ __forceinline__ unsigned short f2b(float f){
    union { float ff; uint32_t i; } v; v.ff = f;
    uint32_t lsb = (v.i >> 16) & 1;
    v.i += 0x7FFFu + lsb;               // RNE
    return (unsigned short)(v.i >> 16);
}
__device__ __forceinline__ uint32_t cvtpk(float lo, float hi){
    uint32_t r;
    asm("v_cvt_pk_bf16_f32 %0, %1, %2" : "=v"(r) : "v"(lo), "v"(hi));
    return r;
}
__device__ __forceinline__ f32x4 mfma16(s16x8 a, s16x8 b, f32x4 c){
    return __builtin_amdgcn_mfma_f32_16x16x32_bf16(a, b, c, 0, 0, 0);
}

template<bool B>
__device__ __forceinline__ float ldin(const void* p, size_t i){
    if (B) return b2f(((const unsigned short*)p)[i]);
    else   return ((const float*)p)[i];
}

// ---------------- inline dtype probe (no flag kernel, no dependency) --------
// bf16: bits[14:7] of each word = exponent of low element, in [120,132] for
// N(0,1) data. f32: mid-mantissa bits, ~5% hit rate. 1024 samples, thr 512.
__device__ bool probe_bf16(const uint32_t* __restrict__ w, int* pc){
    if (threadIdx.x == 0) *pc = 0;
    __syncthreads();
    if (threadIdx.x < 256){
        int local = 0;
        #pragma unroll
        for (int i = 0; i < 4; ++i){
            uint32_t x = w[threadIdx.x*4 + i];
            uint32_t e = (x >> 7) & 0xFFu;
            local += (e >= 120u && e <= 132u) ? 1 : 0;
        }
        if (local) atomicAdd(pc, local);
    }
    __syncthreads();
    return *pc > 512;
}

// ---------------- prep: Gt (blocks 0-255) + wos->Mt (blocks 256-287) --------
template<bool B>
__device__ void gt_body(const void* __restrict__ Wq, const void* __restrict__ Wk,
                        float* __restrict__ Gt, int bx){
    int b = bx, a = threadIdx.x;
    float s = 0.f;
    #pragma unroll 8
    for (int d = 0; d < 256; ++d)
        s += ldin<B>(Wq, (size_t)d*256 + a) * ldin<B>(Wk, (size_t)d*256 + b);
    Gt[b*256 + a] = s;
}
// block owns 8 wos rows (e0..e0+7): wos[e,dp]=sum_h Wo[e,h*256+dp] in LDS,
// then Mt[d*256+e] = sum_dp wos[e,dp]*Wv[dp*256+d] for d = threadIdx.
template<bool B>
__device__ void wosmt_body(const void* __restrict__ Wo, const void* __restrict__ Wv,
                           float* __restrict__ Mt, int bx, float (*sm)[256]){
    int t = threadIdx.x, e0 = bx*8;
    #pragma unroll
    for (int je = 0; je < 8; ++je){
        int e = e0 + je;
        float s = 0.f;
        #pragma unroll
        for (int h = 0; h < 8; ++h) s += ldin<B>(Wo, (size_t)e*2048 + h*256 + t);
        sm[je][t] = s;
    }
    __syncthreads();
    float acc[8] = {0,0,0,0,0,0,0,0};
    #pragma unroll 4
    for (int dp = 0; dp < 256; ++dp){
        float wv = ldin<B>(Wv, (size_t)dp*256 + t);
        #pragma unroll
        for (int je = 0; je < 8; ++je) acc[je] += sm[je][dp] * wv;
    }
    #pragma unroll
    for (int je = 0; je < 8; ++je) Mt[t*256 + e0 + je] = acc[je];
}
__global__ __launch_bounds__(256)
void k_prep(const void* __restrict__ values,
            const void* __restrict__ Wq, const void* __restrict__ Wk,
            const void* __restrict__ Wo, const void* __restrict__ Wv,
            float* __restrict__ Gt, float* __restrict__ Mt){
    __shared__ float sm[8][256];
    __shared__ int pc;
    bool bf = probe_bf16((const uint32_t*)values, &pc);
    if (blockIdx.x < 256){
        if (bf) gt_body<true >(Wq, Wk, Gt, blockIdx.x);
        else    gt_body<false>(Wq, Wk, Gt, blockIdx.x);
    } else {
        int bx = blockIdx.x - 256;
        if (bf) wosmt_body<true >(Wo, Wv, Mt, bx, sm);
        else    wosmt_body<false>(Wo, Wv, Mt, bx, sm);
    }
}

// ---------------- projections -> MFMA B-FRAGMENT-ORDER buffers --------------
// kkF: GEMM1 B-frags. frag(K16=key>>4, ks=e>>5): elem(l,i) =
//      kk[key=K16*16+(l&15)][e=ks*32+((l>>4)&3)*8+i]. 1KB contiguous per frag.
// utF: GEMM2 B-frags. frag(E16=e>>4, ks2=key>>5): elem(l,i) =
//      u[key=ks2*32+((l>>4)&3)*8+i][e=E16*16+(l&15)].
template<bool B>
__device__ void projK_body(const void* __restrict__ A, const float* __restrict__ Wt,
                           unsigned short* __restrict__ C, int bx, float (*As)[256]){
    int r0 = bx * 8;                 // 8 consecutive keys (rows)
    int t  = threadIdx.x;
    #pragma unroll
    for (int j = 0; j < 8; ++j)
        As[j][t] = ldin<B>(A, (size_t)(r0 + j)*256 + t);
    __syncthreads();
    float acc[8] = {0,0,0,0,0,0,0,0};
    #pragma unroll 4
    for (int i = 0; i < 256; ++i){
        float w = Wt[i*256 + t];
        #pragma unroll
        for (int j = 0; j < 8; ++j) acc[j] += As[j][i] * w;
    }
    int nn = r0 >> 9, key0 = r0 & 511;
    int K16 = key0 >> 4, ks = t >> 5, g = (t >> 3) & 3, i = t & 7;
    size_t base = (size_t)nn*PAN + (size_t)((K16*8 + ks)*64)*8;
    int l0 = (key0 & 15) | (g << 4);
    #pragma unroll
    for (int j = 0; j < 8; ++j)
        C[base + (size_t)(l0 + j)*8 + i] = f2b(acc[j]);
}
template<bool B>
__device__ void projU_body(const void* __restrict__ A, const float* __restrict__ Wt,
                           unsigned short* __restrict__ C, int bx, float (*As)[256]){
    int r0 = bx * 8;                 // 8 consecutive keys (rows of u)
    int t  = threadIdx.x;
    #pragma unroll
    for (int j = 0; j < 8; ++j)
        As[j][t] = ldin<B>(A, (size_t)(r0 + j)*256 + t);
    __syncthreads();
    float acc[8] = {0,0,0,0,0,0,0,0};
    #pragma unroll 4
    for (int i = 0; i < 256; ++i){
        float w = Wt[i*256 + t];
        #pragma unroll
        for (int j = 0; j < 8; ++j) acc[j] += As[j][i] * w;
    }
    int nn = r0 >> 9, k0 = r0 & 511;
    int ks2 = k0 >> 5, g = (k0 >> 3) & 3;
    int E16 = t >> 4, l = (t & 15) | (g << 4);
    size_t base = (size_t)nn*PAN + (size_t)((E16*16 + ks2)*64 + l)*8;
    union { s16x8 v; unsigned short h[8]; } pk;
    #pragma unroll
    for (int j = 0; j < 8; ++j) pk.h[j] = f2b(acc[j]);   // j == key&7 == i
    *(s16x8*)(&C[base]) = pk.v;
}
__global__ __launch_bounds__(256)
void k_proj2(const void* __restrict__ keys, const void* __restrict__ values,
             const float* __restrict__ Gt, const float* __restrict__ Mt,
             unsigned short* __restrict__ kkF, unsigned short* __restrict__ utF){
    __shared__ float As[8][256];
    __shared__ int pc;
    bool bf = probe_bf16((const uint32_t*)values, &pc);
    if (blockIdx.x < 512){
        if (bf) projK_body<true >(keys, Gt, kkF, blockIdx.x, As);
        else    projK_body<false>(keys, Gt, kkF, blockIdx.x, As);
    } else {
        int bx = blockIdx.x - 512;
        if (bf) projU_body<true >(values, Mt, utF, bx, As);
        else    projU_body<false>(values, Mt, utF, bx, As);
    }
}

// ---------------- fused: MFMA QK^T -> masked softmax -> MFMA PV -> +bo -------
// 512 threads = 8 waves; 32 q-rows x 512 keys per block; LDS 80KB -> 2 blk/CU.
// B-fragments loaded COALESCED from fragment-order kkF/utF (1KB contiguous per
// frag, 16B/lane) - no LDS staging, no L2 line inflation.
// GEMM1: wave w owns keys [w*64,w*64+64), BOTH row-tiles: acc1[2][4], 64 MFMA.
// GEMM2: wave w owns e-tiles {2w,2w+1}, BOTH row-tiles: acc2[2][2], 64 MFMA.
// A-fragments from XOR-swizzled LDS (Qs bf16 / P bf16) - R2-verified paths.
template<bool B>
__device__ void fused_body(const void* __restrict__ query,
                           const unsigned short* __restrict__ kkF,
                           const unsigned short* __restrict__ utF,
                           const int* __restrict__ mask,
                           const void* __restrict__ bo,
                           void* __restrict__ out,
                           float* Sc, unsigned short* Qs){
    int bid = blockIdx.x;
    int n   = bid & 7;                 // all 64 blocks of a batch on one XCD
    int r0  = (bid >> 3) * BMR;
    int t   = threadIdx.x;
    int l15 = t & 15;
    int g   = (t >> 4) & 3;            // 16-lane group within wave
    int w   = t >> 6;                  // wave 0..7
    int lane = t & 63;

    const unsigned short* Kn = kkF + (size_t)n*PAN;
    const unsigned short* Un = utF + (size_t)n*PAN;
    const int* mn = mask + n*KL;
    unsigned short* P = (unsigned short*)Sc;   // bf16 P aliases Sc[0:32KB)

    // ---- phase 0: stage Q tile to LDS as bf16, XOR-swizzled ----
    {
        int row = t >> 4;              // 0..31
        int c0  = (t & 15) * 16;
        int sw  = (row & 7) << 3;      // 8-elem (16B) granularity
        size_t qoff = (size_t)n*RPN*ED + (size_t)(r0 + row)*ED + c0;
        if (B){
            const unsigned short* qp = (const unsigned short*)query + qoff;
            s16x8 v0 = *(const s16x8*)(qp);
            s16x8 v1 = *(const s16x8*)(qp + 8);
            *(s16x8*)&Qs[(row*ED + c0    ) ^ sw] = v0;
            *(s16x8*)&Qs[(row*ED + c0 + 8) ^ sw] = v1;
        } else {
            const float* qp = (const float*)query + qoff;
            float4 x0 = *(const float4*)(qp);
            float4 x1 = *(const float4*)(qp + 4);
            float4 x2 = *(const float4*)(qp + 8);
            float4 x3 = *(const float4*)(qp + 12);
            union { s16x8 v; uint32_t u[4]; } pk;
            pk.u[0] = cvtpk(x0.x,x0.y); pk.u[1] = cvtpk(x0.z,x0.w);
            pk.u[2] = cvtpk(x1.x,x1.y); pk.u[3] = cvtpk(x1.z,x1.w);
            *(s16x8*)&Qs[(row*ED + c0    ) ^ sw] = pk.v;
            pk.u[0] = cvtpk(x2.x,x2.y); pk.u[1] = cvtpk(x2.z,x2.w);
            pk.u[2] = cvtpk(x3.x,x3.y); pk.u[3] = cvtpk(x3.z,x3.w);
            *(s16x8*)&Qs[(row*ED + c0 + 8) ^ sw] = pk.v;
        }
    }
    __syncthreads();

    int asw = (l15 & 7) << 3;

    // ---- GEMM1: S[32 x 64-key strip] = Q . kk^T ----
    {
        f32x4 acc1[2][4];
        #pragma unroll
        for (int rt = 0; rt < 2; ++rt)
            #pragma unroll
            for (int c = 0; c < 4; ++c) acc1[rt][c] = (f32x4){0.f,0.f,0.f,0.f};

        // frag(kt4, ks) at Kn + ((w*4+kt4)*8 + ks)*512 + lane*8  (coalesced)
        const unsigned short* kb = Kn + (size_t)w*16384 + (size_t)lane*8;
        s16x8 bb[3][4];                // rotating buffer, 2 k-steps ahead
        auto LDK = [&](int KS, int SL){
            #pragma unroll
            for (int c = 0; c < 4; ++c)
                bb[SL][c] = *(const s16x8*)(kb + (size_t)(c*8 + KS)*FRAG);
        };
        LDK(0,0); LDK(1,1);
        #pragma unroll
        for (int ks = 0; ks < 8; ++ks){
            if (ks + 2 < 8) LDK(ks + 2, (ks + 2) % 3);
            int col = ks*32 + g*8;
            s16x8 a0 = *(const s16x8*)&Qs[(( 0 + l15)*ED + col) ^ asw];
            s16x8 a1 = *(const s16x8*)&Qs[((16 + l15)*ED + col) ^ asw];
            #pragma unroll
            for (int c = 0; c < 4; ++c){
                acc1[0][c] = mfma16(a0, bb[ks % 3][c], acc1[0][c]);
                acc1[1][c] = mfma16(a1, bb[ks % 3][c], acc1[1][c]);
            }
        }
        // epilogue: mask + scale -> swizzled LDS (f32)
        #pragma unroll
        for (int c = 0; c < 4; ++c){
            int key = w*64 + c*16 + l15;
            bool zz = (mn[key] == 0);
            #pragma unroll
            for (int rt = 0; rt < 2; ++rt){
                #pragma unroll
                for (int j = 0; j < 4; ++j){
                    int row = rt*16 + g*4 + j;
                    float v = zz ? -1e20f : acc1[rt][c][j] * 0.0625f;
                    Sc[(row*KL + key) ^ ((row & 7) << 2)] = v;
                }
            }
        }
    }
    __syncthreads();

    // ---- masked softmax, 16 threads/row, write P back as bf16 ----
    {
        int row = t >> 4, l16 = t & 15;
        int sw2 = (row & 7) << 2, sw3 = (row & 7) << 3;
        float xs[32];
        float m = -3.0e38f;
        #pragma unroll
        for (int i = 0; i < 32; ++i){
            xs[i] = Sc[(row*KL + l16 + 16*i) ^ sw2];
            m = fmaxf(m, xs[i]);
        }
        #pragma unroll
        for (int off = 1; off < 16; off <<= 1)
            m = fmaxf(m, __shfl_xor(m, off, 16));
        float s = 0.f;
        #pragma unroll
        for (int i = 0; i < 32; ++i){
            xs[i] = __expf(xs[i] - m);
            s += xs[i];
        }
        #pragma unroll
        for (int off = 1; off < 16; off <<= 1)
            s += __shfl_xor(s, off, 16);
        float inv = 1.0f / s;
        __syncthreads();               // all f32 score reads done before aliasing
        #pragma unroll
        for (int i = 0; i < 32; ++i)
            P[(row*KL + l16 + 16*i) ^ sw3] = f2b(xs[i] * inv);
    }
    __syncthreads();

    // ---- GEMM2: Out[32 x 2 e-tiles] = P . u ----
    {
        f32x4 acc2[2][2];
        #pragma unroll
        for (int rt = 0; rt < 2; ++rt)
            #pragma unroll
            for (int c = 0; c < 2; ++c) acc2[rt][c] = (f32x4){0.f,0.f,0.f,0.f};

        // frag(ci, ks2) at Un + ((2w+ci)*16 + ks2)*512 + lane*8  (coalesced)
        const unsigned short* ub = Un + (size_t)(2*w)*8192 + (size_t)lane*8;
        s16x8 bu[3][2];                // rotating buffer, 2 k-steps ahead
        auto LDU = [&](int KS, int SL){
            #pragma unroll
            for (int c = 0; c < 2; ++c)
                bu[SL][c] = *(const s16x8*)(ub + (size_t)(c*16 + KS)*FRAG);
        };
        LDU(0,0); LDU(1,1);
        #pragma unroll
        for (int ks = 0; ks < 16; ++ks){
            if (ks + 2 < 16) LDU(ks + 2, (ks + 2) % 3);
            int col = ks*32 + g*8;
            s16x8 p0 = *(const s16x8*)&P[(( 0 + l15)*KL + col) ^ asw];
            s16x8 p1 = *(const s16x8*)&P[((16 + l15)*KL + col) ^ asw];
            #pragma unroll
            for (int c = 0; c < 2; ++c){
                acc2[0][c] = mfma16(p0, bu[ks % 3][c], acc2[0][c]);
                acc2[1][c] = mfma16(p1, bu[ks % 3][c], acc2[1][c]);
            }
        }
        // epilogue: + bo, store (P already normalized)
        float bov[2];
        #pragma unroll
        for (int c = 0; c < 2; ++c) bov[c] = ldin<B>(bo, (2*w + c)*16 + l15);
        #pragma unroll
        for (int rt = 0; rt < 2; ++rt){
            #pragma unroll
            for (int j = 0; j < 4; ++j){
                int row = rt*16 + g*4 + j;
                #pragma unroll
                for (int c = 0; c < 2; ++c){
                    int e = (2*w + c)*16 + l15;
                    float val = acc2[rt][c][j] + bov[c];
                    size_t oidx = (size_t)n*RPN*ED + (size_t)(r0 + row)*ED + e;
                    if (B) ((unsigned short*)out)[oidx] = f2b(val);
                    else   ((float*)out)[oidx] = val;
                }
            }
        }
    }
}

__global__ __launch_bounds__(512, 4)
void k_fused3(const void* __restrict__ values, const void* __restrict__ query,
              const unsigned short* __restrict__ kkF,
              const unsigned short* __restrict__ utF,
              const int* __restrict__ mask, const void* __restrict__ bo,
              void* __restrict__ out){
    __shared__ float Sc[BMR*KL];           // 64 KB
    __shared__ unsigned short Qs[BMR*ED];  // 16 KB  (total 80 KB -> 2 blocks/CU)
    bool bf = probe_bf16((const uint32_t*)values, (int*)Sc);  // alias, pre-use
    if (bf) fused_body<true >(query, kkF, utF, mask, bo, out, Sc, Qs);
    else    fused_body<false>(query, kkF, utF, mask, bo, out, Sc, Qs);
}

// ---------------- launch ----------------
extern "C" void kernel_launch(void* const* d_in, const int* in_sizes, int n_in,
                              void* d_out, int out_size, void* d_ws, size_t ws_size,
                              hipStream_t stream){
    const void* values = d_in[0];
    const void* keys   = d_in[1];
    const void* query  = d_in[2];
    const int*  mask   = (const int*)d_in[3];
    const void* Wv     = d_in[4];
    const void* Wk     = d_in[5];
    const void* Wq     = d_in[6];
    const void* Wo     = d_in[7];
    const void* bo     = d_in[8];

    // ws layout (floats): [gt 65536][mt 65536][kkF bf16 1Mi elem][utF 1Mi elem]
    float* ws = (float*)d_ws;
    float* ws_gt = ws;
    float* ws_mt = ws + 65536;
    unsigned short* ws_kk = (unsigned short*)(ws + 131072);
    unsigned short* ws_u  = ws_kk + (size_t)NB*PAN;

    k_prep  <<< 288, 256, 0, stream>>>(values, Wq, Wk, Wo, Wv, ws_gt, ws_mt);
    k_proj2 <<<1024, 256, 0, stream>>>(keys, values, ws_gt, ws_mt, ws_kk, ws_u);
    k_fused3<<< 512, 512, 0, stream>>>(values, query, ws_kk, ws_u, mask, bo, d_out);
}